// Round 4
// baseline (2625.567 us; speedup 1.0000x reference)
//
#include <hip/hip_runtime.h>
#include <hip/hip_bf16.h>
#include <stdint.h>

// Problem constants
#define D 1280
#define ND 6
#define BATCH 1024
#define ROWSTRIDE (ND*D)          // 7680
#define WELEM (D*D)
#define WIOF(e) ((e)*WELEM)
#define WOOF(e) ((6+(e))*WELEM)
#define WROF (12*WELEM)
#define WZOF (15*WELEM)
#define WTOF (18*WELEM)
#define WTOT (21*WELEM)
#define ABUF (BATCH*ROWSTRIDE)    // 7,864,320
#define AINO (ABUF)
#define AOUTO (2*ABUF)
#define RGO (3*ABUF)
#define S3D (3*D)
#define SLICE (BATCH*D)           // 1,310,720

typedef unsigned int u32;
typedef unsigned short u16;
typedef __bf16 bf16x8 __attribute__((ext_vector_type(8)));
typedef float f32x4 __attribute__((ext_vector_type(4)));
typedef u16 u16x8 __attribute__((ext_vector_type(8)));

struct Term { int a_off; int b_off; int b_stride; int bias_off; };
struct Job  { int nterms; int epi; int node; int flag; Term t[3]; };

// Edges (src,et,tgt) 0-based: (0,0,1)(0,1,2)(0,2,3)(1,3,2)(1,4,3)(2,5,3)
// jobs 0..11:  phase1 per-edge partials (uniform K=1280). node = partial slice idx.
// jobs 12..27: phase2, XCD-balanced pairs: {3,1}x4, {2,2}x2, {2,1}x2
// jobs 28..33: phase3 (epi4), flag = has tpart
__constant__ Job JOBS[34] = {
  // ---- phase1 per-edge (epi 0)
  {1,0,0, 0, {{0*D, WIOF(0), D, 0*D},{0,0,0,0},{0,0,0,0}}},
  {1,0,1, 0, {{0*D, WIOF(1), D, 1*D},{0,0,0,0},{0,0,0,0}}},
  {1,0,2, 0, {{0*D, WIOF(2), D, 2*D},{0,0,0,0},{0,0,0,0}}},
  {1,0,3, 0, {{1*D, WIOF(3), D, 3*D},{0,0,0,0},{0,0,0,0}}},
  {1,0,4, 0, {{1*D, WIOF(4), D, 4*D},{0,0,0,0},{0,0,0,0}}},
  {1,0,5, 0, {{2*D, WIOF(5), D, 5*D},{0,0,0,0},{0,0,0,0}}},
  {1,0,6, 1, {{1*D, WOOF(0), D, 0*D},{0,0,0,0},{0,0,0,0}}},
  {1,0,7, 1, {{2*D, WOOF(1), D, 1*D},{0,0,0,0},{0,0,0,0}}},
  {1,0,8, 1, {{3*D, WOOF(2), D, 2*D},{0,0,0,0},{0,0,0,0}}},
  {1,0,9, 1, {{2*D, WOOF(3), D, 3*D},{0,0,0,0},{0,0,0,0}}},
  {1,0,10,1, {{3*D, WOOF(4), D, 4*D},{0,0,0,0},{0,0,0,0}}},
  {1,0,11,1, {{3*D, WOOF(5), D, 5*D},{0,0,0,0},{0,0,0,0}}},
  // ---- phase2: {3,1} {3,1} {3,1} {3,1} {2,2} {2,2} {2,1} {2,1}
  {3,1,1,0, {{AINO+1*D, WROF+0*D, S3D, 0},{AOUTO+1*D, WROF+1*D, S3D, 0},{1*D, WROF+2*D, S3D, 0}}},
  {1,1,4,0, {{4*D, WROF+2*D, S3D, 0},{0,0,0,0},{0,0,0,0}}},
  {3,1,2,0, {{AINO+2*D, WROF+0*D, S3D, 0},{AOUTO+2*D, WROF+1*D, S3D, 0},{2*D, WROF+2*D, S3D, 0}}},
  {1,1,5,0, {{5*D, WROF+2*D, S3D, 0},{0,0,0,0},{0,0,0,0}}},
  {3,2,1,0, {{AINO+1*D, WZOF+0*D, S3D, 0},{AOUTO+1*D, WZOF+1*D, S3D, 0},{1*D, WZOF+2*D, S3D, 0}}},
  {1,2,4,0, {{4*D, WZOF+2*D, S3D, 0},{0,0,0,0},{0,0,0,0}}},
  {3,2,2,0, {{AINO+2*D, WZOF+0*D, S3D, 0},{AOUTO+2*D, WZOF+1*D, S3D, 0},{2*D, WZOF+2*D, S3D, 0}}},
  {1,2,5,0, {{5*D, WZOF+2*D, S3D, 0},{0,0,0,0},{0,0,0,0}}},
  {2,1,0,0, {{AOUTO+0*D, WROF+1*D, S3D, 0},{0*D, WROF+2*D, S3D, 0},{0,0,0,0}}},
  {2,1,3,0, {{AINO+3*D, WROF+0*D, S3D, 0},{3*D, WROF+2*D, S3D, 0},{0,0,0,0}}},
  {2,2,0,0, {{AOUTO+0*D, WZOF+1*D, S3D, 0},{0*D, WZOF+2*D, S3D, 0},{0,0,0,0}}},
  {2,2,3,0, {{AINO+3*D, WZOF+0*D, S3D, 0},{3*D, WZOF+2*D, S3D, 0},{0,0,0,0}}},
  {2,3,1,0, {{AINO+1*D, WTOF+0*D, S3D, 0},{AOUTO+1*D, WTOF+1*D, S3D, 0},{0,0,0,0}}},
  {1,3,0,0, {{AOUTO+0*D, WTOF+1*D, S3D, 0},{0,0,0,0},{0,0,0,0}}},
  {2,3,2,0, {{AINO+2*D, WTOF+0*D, S3D, 0},{AOUTO+2*D, WTOF+1*D, S3D, 0},{0,0,0,0}}},
  {1,3,3,0, {{AINO+3*D, WTOF+0*D, S3D, 0},{0,0,0,0},{0,0,0,0}}},
  // ---- phase3
  {1,4,0,1, {{RGO+0*D, WTOF+2*D, S3D, 0},{0,0,0,0},{0,0,0,0}}},
  {1,4,1,1, {{RGO+1*D, WTOF+2*D, S3D, 0},{0,0,0,0},{0,0,0,0}}},
  {1,4,2,1, {{RGO+2*D, WTOF+2*D, S3D, 0},{0,0,0,0},{0,0,0,0}}},
  {1,4,3,1, {{RGO+3*D, WTOF+2*D, S3D, 0},{0,0,0,0},{0,0,0,0}}},
  {1,4,4,0, {{RGO+4*D, WTOF+2*D, S3D, 0},{0,0,0,0},{0,0,0,0}}},
  {1,4,5,0, {{RGO+5*D, WTOF+2*D, S3D, 0},{0,0,0,0},{0,0,0,0}}},
};

struct Cmb { int dst; int np; int p[3]; };
__constant__ Cmb CMBS[6] = {
  {AINO + 1*D, 1, {0,0,0}},
  {AINO + 2*D, 2, {1,3,0}},
  {AINO + 3*D, 3, {2,4,5}},
  {AOUTO+ 0*D, 3, {6,7,8}},
  {AOUTO+ 1*D, 2, {9,10,0}},
  {AOUTO+ 2*D, 1, {11,0,0}},
};

__device__ __forceinline__ void gload16(const void* g, void* l) {
  __builtin_amdgcn_global_load_lds((const __attribute__((address_space(1))) u32*)g,
                                   (__attribute__((address_space(3))) u32*)l, 16, 0, 0);
}
__device__ __forceinline__ float sig_(float x){ return 1.f/(1.f+__expf(-x)); }
__device__ __forceinline__ float tanh_(float x){ float e=__expf(2.f*x); return 1.f-2.f/(e+1.f); }
__device__ __forceinline__ u16 f2b(float f){ __hip_bfloat16 v = __float2bfloat16(f); return *(u16*)&v; }
__device__ __forceinline__ float b2f(u16 v){ return __uint_as_float(((u32)v)<<16); }

__device__ __forceinline__ void bar() {
  asm volatile("" ::: "memory");
  __builtin_amdgcn_s_barrier();
  asm volatile("" ::: "memory");
}
#define VMCNT(n) asm volatile("s_waitcnt vmcnt(" #n ")" ::: "memory")
#define SWZ(r) (((r)&7)<<3)

// Stage half-tile `part` (0/1 = A rows 0-127/128-255, 2/3 = B rows 0-127/128-255) of
// K-tile Ts into dbuf slot Ts&1. LDS dest linear (wave-uniform base + lane*16B);
// source col pre-swizzled with c ^= (r&7)<<3 elems so swizzled ds_reads (same XOR)
// recover linear data (rule #21). 2 gloads / thread / call.
__device__ __forceinline__ void stage_part(int jidx, const u16* __restrict__ act,
    const u16* __restrict__ wb, u16* ls, int m0, int n0, int Ts, int part,
    int lane, int w) {
  const int tm = (Ts >= 40) ? 2 : (Ts >= 20 ? 1 : 0);
  const int kt = Ts - tm*20;
  const Term& t = JOBS[jidx].t[tm];
  const u16* G; int gstr; int row0;
  if (part < 2) { G = act + t.a_off; gstr = ROWSTRIDE;  row0 = m0 + part*128; }
  else          { G = wb  + t.b_off; gstr = t.b_stride; row0 = n0 + (part-2)*128; }
  u16* lbase = ls + (part < 2 ? 0 : 32768) + (((Ts&1)*2 + (part&1))*8192);
  const u16* gk = G + kt*64;
#pragma unroll
  for (int l = 0; l < 2; ++l) {
    const int rb = l*64 + w*8;                 // wave-uniform row base (8 rows/instr)
    const int r  = rb + (lane>>3);
    const int c  = ((lane&7)*8) ^ SWZ(r);
    gload16(gk + (size_t)(row0 + r)*gstr + c, lbase + rb*64);
  }
}

// 256x256 tile, BK=64, 8 waves (2M x 4N), 4-phase counted-vmcnt schedule,
// 8-value XOR swizzle, setprio around MFMA clusters.
// Phase p stages: P1 A0(T+1), P2 A1(T+1), P3 B0(T+2), P4 B1(T+2)+VMCNT(4).
// VMCNT(4) leaves B(T+2)'s 4 loads in flight; guarantees A(T+1) (issued ~2-3
// phases = ~1500cy earlier) landed. Slot overwrite hazards fenced by the
// phase barriers (every ds_read feeds an MFMA before the next barrier).
__global__ __launch_bounds__(512, 2)
void gemm256(u16* __restrict__ act, const u16* __restrict__ wb, u16* __restrict__ part,
             float* __restrict__ gx, float* __restrict__ zbuf, float* __restrict__ tp,
             const float* __restrict__ b_in, const float* __restrict__ b_out,
             const float* __restrict__ b_r, const float* __restrict__ b_z,
             const float* __restrict__ b_t, int job_base) {
  extern __shared__ u16 ls[];   // A: 4 x 8192 u16 (dbuf x half), B same at +32768. 128 KiB.
  const int cpx  = gridDim.x >> 3;
  const int wid  = (blockIdx.x & 7)*cpx + (blockIdx.x >> 3);   // XCD-contiguous
  const int jidx = job_base + wid/20;
  const int tile = wid%20;
  const int m0 = (tile&3)*256;     // M fastest -> B panel shared within XCD chunk
  const int n0 = (tile>>2)*256;
  const int tid  = threadIdx.x;
  const int lane = tid & 63;
  const int w    = tid >> 6;
  const int wm   = w >> 2;       // 0..1  (M half)
  const int wn   = w & 3;        // 0..3  (N quarter)
  const int NT   = JOBS[jidx].nterms * 20;

  f32x4 acc[8][4];
#pragma unroll
  for (int f=0; f<8; ++f)
#pragma unroll
    for (int g=0; g<4; ++g) acc[f][g] = (f32x4)(0.0f);

  // ---- prologue: K-tile 0 fully + B halves of K-tile 1
  stage_part(jidx, act, wb, ls, m0, n0, 0, 0, lane, w);
  stage_part(jidx, act, wb, ls, m0, n0, 0, 1, lane, w);
  stage_part(jidx, act, wb, ls, m0, n0, 0, 2, lane, w);
  stage_part(jidx, act, wb, ls, m0, n0, 0, 3, lane, w);
  stage_part(jidx, act, wb, ls, m0, n0, 1, 2, lane, w);
  stage_part(jidx, act, wb, ls, m0, n0, 1, 3, lane, w);
  VMCNT(4);
  bar();

  const int lr = lane & 15;        // fragment row selector
  const int lc = (lane >> 4) * 8;  // k-offset selector

  for (int T = 0; T < NT; ++T) {
    const int d = T & 1;
    const u16* Ah = ls + (d*2 + wm)*8192;
    const u16* Bh = ls + 32768 + (d*2 + (wn>>1))*8192;
    bf16x8 af[4][2], b01[2][2], b23[2][2];

    // ---- phase 1: read A f0-3 + B g0-1; stage A0(T+1); MFMA quad (qm0,qn0)
#pragma unroll
    for (int fi=0; fi<4; ++fi)
#pragma unroll
      for (int ks=0; ks<2; ++ks) {
        const int r = fi*16 + lr;
        af[fi][ks] = *(const bf16x8*)(Ah + r*64 + ((ks*32 + lc) ^ SWZ(r)));
      }
#pragma unroll
    for (int g=0; g<2; ++g)
#pragma unroll
      for (int ks=0; ks<2; ++ks) {
        const int r = (wn&1)*64 + g*16 + lr;
        b01[g][ks] = *(const bf16x8*)(Bh + r*64 + ((ks*32 + lc) ^ SWZ(r)));
      }
    if (T+1 < NT) stage_part(jidx, act, wb, ls, m0, n0, T+1, 0, lane, w);
    bar();
    __builtin_amdgcn_s_setprio(1);
#pragma unroll
    for (int fi=0; fi<4; ++fi)
#pragma unroll
      for (int g=0; g<2; ++g)
#pragma unroll
        for (int ks=0; ks<2; ++ks)
          acc[fi][g] = __builtin_amdgcn_mfma_f32_16x16x32_bf16(af[fi][ks], b01[g][ks], acc[fi][g], 0,0,0);
    __builtin_amdgcn_s_setprio(0);
    bar();

    // ---- phase 2: read B g2-3; stage A1(T+1); MFMA (qm0,qn1)
#pragma unroll
    for (int g=0; g<2; ++g)
#pragma unroll
      for (int ks=0; ks<2; ++ks) {
        const int r = (wn&1)*64 + (g+2)*16 + lr;
        b23[g][ks] = *(const bf16x8*)(Bh + r*64 + ((ks*32 + lc) ^ SWZ(r)));
      }
    if (T+1 < NT) stage_part(jidx, act, wb, ls, m0, n0, T+1, 1, lane, w);
    bar();
    __builtin_amdgcn_s_setprio(1);
#pragma unroll
    for (int fi=0; fi<4; ++fi)
#pragma unroll
      for (int g=0; g<2; ++g)
#pragma unroll
        for (int ks=0; ks<2; ++ks)
          acc[fi][g+2] = __builtin_amdgcn_mfma_f32_16x16x32_bf16(af[fi][ks], b23[g][ks], acc[fi][g+2], 0,0,0);
    __builtin_amdgcn_s_setprio(0);
    bar();

    // ---- phase 3: read A f4-7; stage B0(T+2); MFMA (qm1,qn0)
#pragma unroll
    for (int fi=0; fi<4; ++fi)
#pragma unroll
      for (int ks=0; ks<2; ++ks) {
        const int r = (fi+4)*16 + lr;
        af[fi][ks] = *(const bf16x8*)(Ah + r*64 + ((ks*32 + lc) ^ SWZ(r)));
      }
    if (T+2 < NT) stage_part(jidx, act, wb, ls, m0, n0, T+2, 2, lane, w);
    bar();
    __builtin_amdgcn_s_setprio(1);
#pragma unroll
    for (int fi=0; fi<4; ++fi)
#pragma unroll
      for (int g=0; g<2; ++g)
#pragma unroll
        for (int ks=0; ks<2; ++ks)
          acc[fi+4][g] = __builtin_amdgcn_mfma_f32_16x16x32_bf16(af[fi][ks], b01[g][ks], acc[fi+4][g], 0,0,0);
    __builtin_amdgcn_s_setprio(0);
    bar();

    // ---- phase 4: stage B1(T+2); counted vmcnt (A(T+1) landed); MFMA (qm1,qn1)
    if (T+2 < NT) {
      stage_part(jidx, act, wb, ls, m0, n0, T+2, 3, lane, w);
      VMCNT(4);
    } else {
      VMCNT(0);
    }
    bar();
    __builtin_amdgcn_s_setprio(1);
#pragma unroll
    for (int fi=0; fi<4; ++fi)
#pragma unroll
      for (int g=0; g<2; ++g)
#pragma unroll
        for (int ks=0; ks<2; ++ks)
          acc[fi+4][g+2] = __builtin_amdgcn_mfma_f32_16x16x32_bf16(af[fi][ks], b23[g][ks], acc[fi+4][g+2], 0,0,0);
    __builtin_amdgcn_s_setprio(0);
    bar();
  }

  // ---- epilogue. C frag mapping: col = lane&15, row = (lane>>4)*4 + reg.
  const int epi  = JOBS[jidx].epi;
  const int node = JOBS[jidx].node;
  const int flag = JOBS[jidx].flag;
  const int r0 = m0 + wm*128 + ((lane>>4)<<2);
  const int c0 = n0 + wn*64 + lr;

  if (epi == 0) {
    const float* bias = (flag ? b_out : b_in) + JOBS[jidx].t[0].bias_off;
    u16* outp = part + (size_t)node*SLICE;
#pragma unroll
    for (int g=0; g<4; ++g) {
      const int col = c0 + g*16;
      const float bv = bias[col];
#pragma unroll
      for (int f=0; f<8; ++f)
#pragma unroll
        for (int r=0; r<4; ++r)
          outp[(size_t)(r0 + f*16 + r)*D + col] = f2b(acc[f][g][r] + bv);
    }
  } else if (epi == 1) {
#pragma unroll
    for (int g=0; g<4; ++g) {
      const int col = c0 + g*16;
      const float bv = b_r[col];
#pragma unroll
      for (int f=0; f<8; ++f)
#pragma unroll
        for (int r=0; r<4; ++r) {
          const size_t idx = (size_t)(r0 + f*16 + r)*ROWSTRIDE + node*D + col;
          act[RGO + idx] = f2b(sig_(acc[f][g][r] + bv) * gx[idx]);
        }
    }
  } else if (epi == 2) {
#pragma unroll
    for (int g=0; g<4; ++g) {
      const int col = c0 + g*16;
      const float bv = b_z[col];
#pragma unroll
      for (int f=0; f<8; ++f)
#pragma unroll
        for (int r=0; r<4; ++r) {
          const size_t idx = (size_t)(r0 + f*16 + r)*ROWSTRIDE + node*D + col;
          zbuf[idx] = sig_(acc[f][g][r] + bv);
        }
    }
  } else if (epi == 3) {
#pragma unroll
    for (int g=0; g<4; ++g) {
      const int col = c0 + g*16;
#pragma unroll
      for (int f=0; f<8; ++f)
#pragma unroll
        for (int r=0; r<4; ++r) {
          const size_t idx = (size_t)(r0 + f*16 + r)*ROWSTRIDE + node*D + col;
          tp[idx] = acc[f][g][r];
        }
    }
  } else {
#pragma unroll
    for (int g=0; g<4; ++g) {
      const int col = c0 + g*16;
      const float bv = b_t[col];
#pragma unroll
      for (int f=0; f<8; ++f)
#pragma unroll
        for (int r=0; r<4; ++r) {
          const size_t idx = (size_t)(r0 + f*16 + r)*ROWSTRIDE + node*D + col;
          float tv = acc[f][g][r] + bv + (flag ? tp[idx] : 0.f);
          float h  = tanh_(tv);
          float zv = zbuf[idx];
          float gv = gx[idx];
          float ng = (1.f - zv)*gv + zv*h;
          gx[idx]  = ng;
          act[idx] = f2b(ng);
        }
    }
  }
}

// Sum per-edge partial slices (+bias already applied) into AIN/AOUT bf16 slices.
__global__ void combine(u16* __restrict__ act, const u16* __restrict__ part) {
  const int bid = blockIdx.x;
  const int s = bid/640;
  const int idx = (bid%640)*256 + threadIdx.x;   // 0..163839
  const int row = idx/160, c8 = (idx%160)*8;
  const Cmb& cb = CMBS[s];
  float sum[8];
#pragma unroll
  for (int q=0;q<8;q++) sum[q]=0.f;
  for (int i=0;i<cb.np;i++) {
    const u16x8 v = *(const u16x8*)(part + (size_t)cb.p[i]*SLICE + (size_t)row*D + c8);
#pragma unroll
    for (int q=0;q<8;q++) sum[q] += b2f(v[q]);
  }
  u16x8 o;
#pragma unroll
  for (int q=0;q<8;q++) o[q] = f2b(sum[q]);
  *(u16x8*)(act + (size_t)cb.dst + (size_t)row*ROWSTRIDE + c8) = o;
}

// Transpose-convert all weights fp32 -> bf16 (rows = output col n, cols = k).
__global__ void conv_weights(const float* __restrict__ wi, const float* __restrict__ wo,
                             const float* __restrict__ wr, const float* __restrict__ wz,
                             const float* __restrict__ wt, u16* __restrict__ wb) {
  int bid = blockIdx.x;
  int base = 0; int j = 0;
  for (; j < 15; ++j) {
    int R_ = (j < 12) ? 1280 : 3840;
    int tiles = (R_/32)*40;
    if (bid < base + tiles) break;
    base += tiles;
  }
  const int R = (j < 12) ? 1280 : 3840;
  const int C = 1280;
  const float* src; int doff;
  if (j < 6)        { src = wi + (size_t)j*WELEM;     doff = WIOF(j); }
  else if (j < 12)  { src = wo + (size_t)(j-6)*WELEM; doff = WOOF(j-6); }
  else if (j == 12) { src = wr;                       doff = WROF; }
  else if (j == 13) { src = wz;                       doff = WZOF; }
  else              { src = wt;                       doff = WTOF; }
  int tt = bid - base;
  int tr = tt / 40, tc = tt % 40;
  __shared__ float tile[32][33];
  int tx = threadIdx.x, ty = threadIdx.y;
#pragma unroll
  for (int k=0;k<4;k++)
    tile[ty+8*k][tx] = src[(size_t)(tr*32+ty+8*k)*C + tc*32+tx];
  __syncthreads();
  u16* dst = wb + doff;
#pragma unroll
  for (int k=0;k<4;k++)
    dst[(size_t)(tc*32+ty+8*k)*R + tr*32+tx] = f2b(tile[tx][ty+8*k]);
}

__global__ void init_gx(const float* __restrict__ x, float* __restrict__ gx, u16* __restrict__ gxb) {
  for (size_t i = (size_t)blockIdx.x*blockDim.x + threadIdx.x; i < (size_t)ABUF;
       i += (size_t)gridDim.x*blockDim.x) {
    float v = x[i];
    gx[i] = v;
    gxb[i] = f2b(v);
  }
}

// out[b, d*6+n] = gx[b, n, d]
__global__ void final_out(const float* __restrict__ gx, float* __restrict__ out) {
  int b = blockIdx.x;
  const float* g = gx + (size_t)b*ROWSTRIDE;
  float* o = out + (size_t)b*ROWSTRIDE;
  for (int jj = threadIdx.x; jj < ROWSTRIDE; jj += blockDim.x) {
    int n = jj % ND, d = jj / ND;
    o[jj] = g[n*D + d];
  }
}

extern "C" void kernel_launch(void* const* d_in, const int* in_sizes, int n_in,
                              void* d_out, int out_size, void* d_ws, size_t ws_size,
                              hipStream_t stream) {
  (void)in_sizes; (void)n_in; (void)out_size; (void)ws_size;
  const float* x  = (const float*)d_in[0];
  const float* Wi = (const float*)d_in[2];
  const float* bi = (const float*)d_in[3];
  const float* Wo = (const float*)d_in[4];
  const float* bo = (const float*)d_in[5];
  const float* Wr = (const float*)d_in[6];
  const float* br = (const float*)d_in[7];
  const float* Wz = (const float*)d_in[8];
  const float* bz = (const float*)d_in[9];
  const float* Wt = (const float*)d_in[10];
  const float* bt = (const float*)d_in[11];
  float* out = (float*)d_out;

  u16* wb  = (u16*)d_ws;                       // 21*WELEM bf16
  u16* act = wb + WTOT;                        // 4*ABUF bf16: [gxb | AIN | AOUT | rg]
  float* gxp = (float*)(act + (size_t)4*ABUF); // fp32 master state
  float* zb  = gxp + ABUF;
  float* tpp = zb + ABUF;                      // fp32 tpart; aliased as 12 bf16 partial slices
  u16* partp = (u16*)tpp;                      // (partials dead before tpart written)

  conv_weights<<<33600, dim3(32,8,1), 0, stream>>>(Wi, Wo, Wr, Wz, Wt, wb);
  init_gx<<<2048, 256, 0, stream>>>(x, gxp, act);
  for (int s = 0; s < 5; ++s) {
    gemm256<<<240, 512, 131072, stream>>>(act, wb, partp, gxp, zb, tpp, bi, bo, br, bz, bt, 0);
    combine<<<3840, 256, 0, stream>>>(act, partp);
    gemm256<<<320, 512, 131072, stream>>>(act, wb, partp, gxp, zb, tpp, bi, bo, br, bz, bt, 12);
    gemm256<<<120, 512, 131072, stream>>>(act, wb, partp, gxp, zb, tpp, bi, bo, br, bz, bt, 28);
  }
  final_out<<<BATCH, 256, 0, stream>>>(gxp, out);
}

// Round 5
// 1559.806 us; speedup vs baseline: 1.6833x; 1.6833x over previous
//
#include <hip/hip_runtime.h>
#include <hip/hip_bf16.h>
#include <stdint.h>

// Problem constants
#define D 1280
#define ND 6
#define BATCH 1024
#define ROWSTRIDE (ND*D)          // 7680
#define WELEM (D*D)
#define WIOF(e) ((e)*WELEM)
#define WOOF(e) ((6+(e))*WELEM)
#define WROF (12*WELEM)
#define WZOF (15*WELEM)
#define WTOF (18*WELEM)
#define WTOT (21*WELEM)
#define ABUF (BATCH*ROWSTRIDE)    // 7,864,320
#define AINO (ABUF)
#define AOUTO (2*ABUF)
#define RGO (3*ABUF)
#define S3D (3*D)
#define SLICE (BATCH*D)           // 1,310,720

typedef unsigned int u32;
typedef unsigned short u16;
typedef __bf16 bf16x8 __attribute__((ext_vector_type(8)));
typedef float f32x4 __attribute__((ext_vector_type(4)));
typedef u16 u16x8 __attribute__((ext_vector_type(8)));

struct Term { int a_off; int b_off; int b_stride; int bias_off; };
struct Job  { int nterms; int epi; int node; int flag; Term t[3]; };

// Edges (src,et,tgt) 0-based: (0,0,1)(0,1,2)(0,2,3)(1,3,2)(1,4,3)(2,5,3)
// jobs 0..11:  phase1 per-edge partials (uniform K=1280). node = partial slice idx.
// jobs 12..27: phase2 r/z/tpart
// jobs 28..33: phase3 (epi4), flag = has tpart
__constant__ Job JOBS[34] = {
  // ---- phase1 per-edge (epi 0): Pin[e]=gxb(src)@W_in[et], Pout[e]=gxb(tgt)@W_out[et]
  {1,0,0, 0, {{0*D, WIOF(0), D, 0*D},{0,0,0,0},{0,0,0,0}}},
  {1,0,1, 0, {{0*D, WIOF(1), D, 1*D},{0,0,0,0},{0,0,0,0}}},
  {1,0,2, 0, {{0*D, WIOF(2), D, 2*D},{0,0,0,0},{0,0,0,0}}},
  {1,0,3, 0, {{1*D, WIOF(3), D, 3*D},{0,0,0,0},{0,0,0,0}}},
  {1,0,4, 0, {{1*D, WIOF(4), D, 4*D},{0,0,0,0},{0,0,0,0}}},
  {1,0,5, 0, {{2*D, WIOF(5), D, 5*D},{0,0,0,0},{0,0,0,0}}},
  {1,0,6, 1, {{1*D, WOOF(0), D, 0*D},{0,0,0,0},{0,0,0,0}}},
  {1,0,7, 1, {{2*D, WOOF(1), D, 1*D},{0,0,0,0},{0,0,0,0}}},
  {1,0,8, 1, {{3*D, WOOF(2), D, 2*D},{0,0,0,0},{0,0,0,0}}},
  {1,0,9, 1, {{2*D, WOOF(3), D, 3*D},{0,0,0,0},{0,0,0,0}}},
  {1,0,10,1, {{3*D, WOOF(4), D, 4*D},{0,0,0,0},{0,0,0,0}}},
  {1,0,11,1, {{3*D, WOOF(5), D, 5*D},{0,0,0,0},{0,0,0,0}}},
  // ---- phase2 (16 jobs)
  {3,1,1,0, {{AINO+1*D, WROF+0*D, S3D, 0},{AOUTO+1*D, WROF+1*D, S3D, 0},{1*D, WROF+2*D, S3D, 0}}},
  {1,1,4,0, {{4*D, WROF+2*D, S3D, 0},{0,0,0,0},{0,0,0,0}}},
  {3,1,2,0, {{AINO+2*D, WROF+0*D, S3D, 0},{AOUTO+2*D, WROF+1*D, S3D, 0},{2*D, WROF+2*D, S3D, 0}}},
  {1,1,5,0, {{5*D, WROF+2*D, S3D, 0},{0,0,0,0},{0,0,0,0}}},
  {3,2,1,0, {{AINO+1*D, WZOF+0*D, S3D, 0},{AOUTO+1*D, WZOF+1*D, S3D, 0},{1*D, WZOF+2*D, S3D, 0}}},
  {1,2,4,0, {{4*D, WZOF+2*D, S3D, 0},{0,0,0,0},{0,0,0,0}}},
  {3,2,2,0, {{AINO+2*D, WZOF+0*D, S3D, 0},{AOUTO+2*D, WZOF+1*D, S3D, 0},{2*D, WZOF+2*D, S3D, 0}}},
  {1,2,5,0, {{5*D, WZOF+2*D, S3D, 0},{0,0,0,0},{0,0,0,0}}},
  {2,1,0,0, {{AOUTO+0*D, WROF+1*D, S3D, 0},{0*D, WROF+2*D, S3D, 0},{0,0,0,0}}},
  {2,1,3,0, {{AINO+3*D, WROF+0*D, S3D, 0},{3*D, WROF+2*D, S3D, 0},{0,0,0,0}}},
  {2,2,0,0, {{AOUTO+0*D, WZOF+1*D, S3D, 0},{0*D, WZOF+2*D, S3D, 0},{0,0,0,0}}},
  {2,2,3,0, {{AINO+3*D, WZOF+0*D, S3D, 0},{3*D, WZOF+2*D, S3D, 0},{0,0,0,0}}},
  {2,3,1,0, {{AINO+1*D, WTOF+0*D, S3D, 0},{AOUTO+1*D, WTOF+1*D, S3D, 0},{0,0,0,0}}},
  {1,3,0,0, {{AOUTO+0*D, WTOF+1*D, S3D, 0},{0,0,0,0},{0,0,0,0}}},
  {2,3,2,0, {{AINO+2*D, WTOF+0*D, S3D, 0},{AOUTO+2*D, WTOF+1*D, S3D, 0},{0,0,0,0}}},
  {1,3,3,0, {{AINO+3*D, WTOF+0*D, S3D, 0},{0,0,0,0},{0,0,0,0}}},
  // ---- phase3
  {1,4,0,1, {{RGO+0*D, WTOF+2*D, S3D, 0},{0,0,0,0},{0,0,0,0}}},
  {1,4,1,1, {{RGO+1*D, WTOF+2*D, S3D, 0},{0,0,0,0},{0,0,0,0}}},
  {1,4,2,1, {{RGO+2*D, WTOF+2*D, S3D, 0},{0,0,0,0},{0,0,0,0}}},
  {1,4,3,1, {{RGO+3*D, WTOF+2*D, S3D, 0},{0,0,0,0},{0,0,0,0}}},
  {1,4,4,0, {{RGO+4*D, WTOF+2*D, S3D, 0},{0,0,0,0},{0,0,0,0}}},
  {1,4,5,0, {{RGO+5*D, WTOF+2*D, S3D, 0},{0,0,0,0},{0,0,0,0}}},
};

struct Cmb { int dst; int np; int p[3]; };
__constant__ Cmb CMBS[6] = {
  {AINO + 1*D, 1, {0,0,0}},
  {AINO + 2*D, 2, {1,3,0}},
  {AINO + 3*D, 3, {2,4,5}},
  {AOUTO+ 0*D, 3, {6,7,8}},
  {AOUTO+ 1*D, 2, {9,10,0}},
  {AOUTO+ 2*D, 1, {11,0,0}},
};

__device__ __forceinline__ void gload16(const void* g, void* l) {
  __builtin_amdgcn_global_load_lds((const __attribute__((address_space(1))) u32*)g,
                                   (__attribute__((address_space(3))) u32*)l, 16, 0, 0);
}
__device__ __forceinline__ float sig_(float x){ return 1.f/(1.f+__expf(-x)); }
__device__ __forceinline__ float tanh_(float x){ float e=__expf(2.f*x); return 1.f-2.f/(e+1.f); }
__device__ __forceinline__ u16 f2b(float f){ __hip_bfloat16 v = __float2bfloat16(f); return *(u16*)&v; }
__device__ __forceinline__ float b2f(u16 v){ return __uint_as_float(((u32)v)<<16); }
#define SWZ(r) (((r)&7)<<3)

// Stage one 128x64 A tile + one 128x64 B tile into LDS (linear dest, wave-uniform base).
// Source column pre-swizzled with c ^= (r&7)<<3 so swizzled ds_reads recover linear data.
__device__ __forceinline__ void stageAB(const u16* __restrict__ A, const u16* __restrict__ Bb,
    int bstr, u16* la, u16* lb, int kk, int tid) {
  const int rr = tid >> 3;                  // wave-consistent: w*8 + (lane>>3)
  const int ce = (tid & 7) * 8;
  const int wbase = (tid >> 6) * 512;       // wave-uniform LDS offset within 32-row chunk
#pragma unroll
  for (int c4 = 0; c4 < 4; ++c4) {
    const int r  = c4*32 + rr;
    const int cs = ce ^ SWZ(r);
    gload16(A  + (size_t)r*ROWSTRIDE + (size_t)kk + cs, la + c4*2048 + wbase);
    gload16(Bb + (size_t)r*bstr      + (size_t)kk + cs, lb + c4*2048 + wbase);
  }
}

// 128x128 tile, BK=64, 4 waves, double-buffered LDS, prefetch-1, one barrier per K-tile.
// Work mapping: N-panel -> XCD affinity (bid%8 = XCD). XCD x owns panel x entirely
// (NJ jobs x 8 M-tiles = U units); panels 8,9 split evenly across XCDs. This pins each
// 128-col weight panel (2.9-3.8 MB bf16) in ONE XCD's 4MB L2 -> staging L2-hits.
__global__ __launch_bounds__(256, 2)
void gemm_batched(u16* __restrict__ act, const u16* __restrict__ wb, u16* __restrict__ part,
                  float* __restrict__ gx, float* __restrict__ zbuf, float* __restrict__ tp,
                  const float* __restrict__ b_in, const float* __restrict__ b_out,
                  const float* __restrict__ b_r, const float* __restrict__ b_z,
                  const float* __restrict__ b_t, int job_base, int NJ) {
  __shared__ __align__(16) u16 lsA[2][128*64];   // 32 KiB
  __shared__ __align__(16) u16 lsB[2][128*64];   // 32 KiB
  const int U   = NJ << 3;                 // units per panel
  const int xcd = blockIdx.x & 7;
  const int s   = blockIdx.x >> 3;         // slot within XCD, [0, U + U/4)
  int panel, u;
  if (s < U) { panel = xcd; u = s; }
  else {
    const int g = xcd*(U>>2) + (s - U);    // [0, 2U)
    const int hi = (g >= U);
    panel = 8 + hi; u = g - (hi ? U : 0);
  }
  const int job = u >> 3;
  const int m0  = (u & 7) * 128;
  const int n0  = panel * 128;
  const int tid  = threadIdx.x;
  const int lane = tid & 63;
  const int w    = tid >> 6;
  const int wm   = (w >> 1) << 6;
  const int wn   = (w & 1) << 6;
  const Job jb = JOBS[job_base + job];
  const int NT = jb.nterms * 20;

  const u16* At[3]; const u16* Bt[3]; int bs[3];
#pragma unroll
  for (int i=0;i<3;i++) {
    At[i] = act + jb.t[i].a_off + (size_t)m0*ROWSTRIDE;
    Bt[i] = wb  + jb.t[i].b_off + (size_t)n0*jb.t[i].b_stride;
    bs[i] = jb.t[i].b_stride;
  }

  f32x4 acc[4][4];
#pragma unroll
  for (int i=0;i<4;i++)
#pragma unroll
    for (int j=0;j<4;j++) acc[i][j] = (f32x4)(0.0f);

  // prologue: stage K-tile 0 into buf 0
  stageAB(At[0], Bt[0], bs[0], lsA[0], lsB[0], 0, tid);
  __syncthreads();

  const int lr = lane & 15;
  const int lc = (lane >> 4) * 8;

  for (int t = 0; t < NT; ++t) {
    // issue next tile's staging FIRST; end-of-iter __syncthreads is the only drain point
    if (t+1 < NT) {
      const int tm = (t+1)/20;
      const int kk = ((t+1)%20)*64;
      stageAB(At[tm], Bt[tm], bs[tm], lsA[(t+1)&1], lsB[(t+1)&1], kk, tid);
    }
    const u16* la = lsA[t&1];
    const u16* lb = lsB[t&1];
#pragma unroll
    for (int ks=0; ks<2; ++ks) {
      bf16x8 af[4], bfr[4];
#pragma unroll
      for (int i=0;i<4;i++) {
        const int ra = wm + i*16 + lr;
        af[i]  = *(const bf16x8*)(la + ra*64 + ((ks*32 + lc) ^ SWZ(ra)));
        const int rb = wn + i*16 + lr;
        bfr[i] = *(const bf16x8*)(lb + rb*64 + ((ks*32 + lc) ^ SWZ(rb)));
      }
#pragma unroll
      for (int i=0;i<4;i++)
#pragma unroll
        for (int j=0;j<4;j++)
          acc[i][j] = __builtin_amdgcn_mfma_f32_16x16x32_bf16(af[i], bfr[j], acc[i][j], 0,0,0);
    }
    __syncthreads();
  }

  // Epilogue. C frag mapping: col = lane&15, row = (lane>>4)*4 + reg.
  const int r0 = m0 + wm + ((lane>>4)<<2);
  const int c0 = n0 + wn + lr;
  const int node = jb.node;

  if (jb.epi == 0) {
    const float* bias = (jb.flag ? b_out : b_in) + jb.t[0].bias_off;
    u16* outp = part + (size_t)node*SLICE;
#pragma unroll
    for (int j=0;j<4;j++) {
      const int col = c0 + j*16;
      const float bv = bias[col];
#pragma unroll
      for (int i=0;i<4;i++)
#pragma unroll
        for (int r=0;r<4;r++)
          outp[(size_t)(r0 + i*16 + r)*D + col] = f2b(acc[i][j][r] + bv);
    }
  } else if (jb.epi == 1) {
#pragma unroll
    for (int i=0;i<4;i++)
#pragma unroll
      for (int j=0;j<4;j++)
#pragma unroll
        for (int r=0;r<4;r++) {
          int row = r0 + i*16 + r, col = c0 + j*16;
          size_t idx = (size_t)row*ROWSTRIDE + node*D + col;
          float rr = sig_(acc[i][j][r] + b_r[col]);
          act[RGO + idx] = f2b(rr * gx[idx]);
        }
  } else if (jb.epi == 2) {
#pragma unroll
    for (int i=0;i<4;i++)
#pragma unroll
      for (int j=0;j<4;j++)
#pragma unroll
        for (int r=0;r<4;r++) {
          int row = r0 + i*16 + r, col = c0 + j*16;
          size_t idx = (size_t)row*ROWSTRIDE + node*D + col;
          zbuf[idx] = sig_(acc[i][j][r] + b_z[col]);
        }
  } else if (jb.epi == 3) {
#pragma unroll
    for (int i=0;i<4;i++)
#pragma unroll
      for (int j=0;j<4;j++)
#pragma unroll
        for (int r=0;r<4;r++) {
          int row = r0 + i*16 + r, col = c0 + j*16;
          size_t idx = (size_t)row*ROWSTRIDE + node*D + col;
          tp[idx] = acc[i][j][r];
        }
  } else {
#pragma unroll
    for (int i=0;i<4;i++)
#pragma unroll
      for (int j=0;j<4;j++)
#pragma unroll
        for (int r=0;r<4;r++) {
          int row = r0 + i*16 + r, col = c0 + j*16;
          size_t idx = (size_t)row*ROWSTRIDE + node*D + col;
          float tv = acc[i][j][r] + b_t[col] + (jb.flag ? tp[idx] : 0.f);
          float h = tanh_(tv);
          float zv = zbuf[idx];
          float g = gx[idx];
          float ng = (1.f - zv)*g + zv*h;
          gx[idx] = ng;
          act[idx] = f2b(ng);   // gxb for next step
        }
  }
}

// Sum per-edge partial slices (+bias already applied) into AIN/AOUT bf16 slices.
__global__ void combine(u16* __restrict__ act, const u16* __restrict__ part) {
  const int bid = blockIdx.x;
  const int s = bid/640;
  const int idx = (bid%640)*256 + threadIdx.x;   // 0..163839
  const int row = idx/160, c8 = (idx%160)*8;
  const Cmb& cb = CMBS[s];
  float sum[8];
#pragma unroll
  for (int q=0;q<8;q++) sum[q]=0.f;
  for (int i=0;i<cb.np;i++) {
    const u16x8 v = *(const u16x8*)(part + (size_t)cb.p[i]*SLICE + (size_t)row*D + c8);
#pragma unroll
    for (int q=0;q<8;q++) sum[q] += b2f(v[q]);
  }
  u16x8 o;
#pragma unroll
  for (int q=0;q<8;q++) o[q] = f2b(sum[q]);
  *(u16x8*)(act + (size_t)cb.dst + (size_t)row*ROWSTRIDE + c8) = o;
}

// Transpose-convert all weights fp32 -> bf16 (rows = output col n, cols = k).
__global__ void conv_weights(const float* __restrict__ wi, const float* __restrict__ wo,
                             const float* __restrict__ wr, const float* __restrict__ wz,
                             const float* __restrict__ wt, u16* __restrict__ wb) {
  int bid = blockIdx.x;
  int base = 0; int j = 0;
  for (; j < 15; ++j) {
    int R_ = (j < 12) ? 1280 : 3840;
    int tiles = (R_/32)*40;
    if (bid < base + tiles) break;
    base += tiles;
  }
  const int R = (j < 12) ? 1280 : 3840;
  const int C = 1280;
  const float* src; int doff;
  if (j < 6)        { src = wi + (size_t)j*WELEM;     doff = WIOF(j); }
  else if (j < 12)  { src = wo + (size_t)(j-6)*WELEM; doff = WOOF(j-6); }
  else if (j == 12) { src = wr;                       doff = WROF; }
  else if (j == 13) { src = wz;                       doff = WZOF; }
  else              { src = wt;                       doff = WTOF; }
  int tt = bid - base;
  int tr = tt / 40, tc = tt % 40;
  __shared__ float tile[32][33];
  int tx = threadIdx.x, ty = threadIdx.y;
#pragma unroll
  for (int k=0;k<4;k++)
    tile[ty+8*k][tx] = src[(size_t)(tr*32+ty+8*k)*C + tc*32+tx];
  __syncthreads();
  u16* dst = wb + doff;
#pragma unroll
  for (int k=0;k<4;k++)
    dst[(size_t)(tc*32+ty+8*k)*R + tr*32+tx] = f2b(tile[tx][ty+8*k]);
}

__global__ void init_gx(const float* __restrict__ x, float* __restrict__ gx, u16* __restrict__ gxb) {
  for (size_t i = (size_t)blockIdx.x*blockDim.x + threadIdx.x; i < (size_t)ABUF;
       i += (size_t)gridDim.x*blockDim.x) {
    float v = x[i];
    gx[i] = v;
    gxb[i] = f2b(v);
  }
}

// out[b, d*6+n] = gx[b, n, d]
__global__ void final_out(const float* __restrict__ gx, float* __restrict__ out) {
  int b = blockIdx.x;
  const float* g = gx + (size_t)b*ROWSTRIDE;
  float* o = out + (size_t)b*ROWSTRIDE;
  for (int jj = threadIdx.x; jj < ROWSTRIDE; jj += blockDim.x) {
    int n = jj % ND, d = jj / ND;
    o[jj] = g[n*D + d];
  }
}

extern "C" void kernel_launch(void* const* d_in, const int* in_sizes, int n_in,
                              void* d_out, int out_size, void* d_ws, size_t ws_size,
                              hipStream_t stream) {
  (void)in_sizes; (void)n_in; (void)out_size; (void)ws_size;
  const float* x  = (const float*)d_in[0];
  const float* Wi = (const float*)d_in[2];
  const float* bi = (const float*)d_in[3];
  const float* Wo = (const float*)d_in[4];
  const float* bo = (const float*)d_in[5];
  const float* Wr = (const float*)d_in[6];
  const float* br = (const float*)d_in[7];
  const float* Wz = (const float*)d_in[8];
  const float* bz = (const float*)d_in[9];
  const float* Wt = (const float*)d_in[10];
  const float* bt = (const float*)d_in[11];
  float* out = (float*)d_out;

  u16* wb  = (u16*)d_ws;                       // 21*WELEM bf16
  u16* act = wb + WTOT;                        // 4*ABUF bf16: [gxb | AIN | AOUT | rg]
  float* gxp = (float*)(act + (size_t)4*ABUF); // fp32 master state
  float* zb  = gxp + ABUF;
  float* tpp = zb + ABUF;                      // fp32 tpart; aliased as 12 bf16 partial slices
  u16* partp = (u16*)tpp;                      // (partials dead before tpart written)

  conv_weights<<<33600, dim3(32,8,1), 0, stream>>>(Wi, Wo, Wr, Wz, Wt, wb);
  init_gx<<<2048, 256, 0, stream>>>(x, gxp, act);
  for (int s = 0; s < 5; ++s) {
    // grids: NXCD * (U + U/4) with U = NJ*8  ->  phase1: 8*120=960, phase2: 8*160=1280, phase3: 8*60=480
    gemm_batched<<<960, 256, 0, stream>>>(act, wb, partp, gxp, zb, tpp, bi, bo, br, bz, bt, 0, 12);
    combine<<<3840, 256, 0, stream>>>(act, partp);
    gemm_batched<<<1280,256, 0, stream>>>(act, wb, partp, gxp, zb, tpp, bi, bo, br, bz, bt, 12, 16);
    gemm_batched<<<480, 256, 0, stream>>>(act, wb, partp, gxp, zb, tpp, bi, bo, br, bz, bt, 28, 6);
  }
  final_out<<<BATCH, 256, 0, stream>>>(gxp, out);
}